// Round 15
// baseline (868.401 us; speedup 1.0000x reference)
//
#include <hip/hip_runtime.h>
#include <math.h>

// ---------------------------------------------------------------------------
// SGCN forward — CSR pull aggregation + MFMA dense layers.
//
// R19: R18's cooperative fusion failed because ROCm's grid.sync does
// system-scope cache flush per arrival (WRITE 187MB vs 38MB real; waves
// spinning 280us at 7.7% VALU). The fusion theory stands (R17 calibration:
// ~9-13us gap per stream op, 8 ops). Replacement mechanism, no cache flush:
//   * ag is the ONLY cross-block data inside a fused layer -> written via
//     agent-scope 8B atomic stores (L2-bypass to device-coherent point),
//     read via agent-scope loads. No L2 writeback needed at the barrier.
//   * barrier = atomicAdd(release) + tid0 relaxed spin + s_sleep backoff +
//     failsafe bound (wrong-answer, never hang).
//   * deadlock safety: LB(256,7) => capacity >= 1792 blocks; grid 1536
//     (>=256 slots slack). Stream ops 7 -> 5.
// Build (memset+mega+scatter) = R16 verbatim. agg structure frozen (R11
// fabric-ceiling probe); replica reserve (R14); XCD nmap (R16).
// ---------------------------------------------------------------------------

typedef _Float16 h4 __attribute__((ext_vector_type(4)));
typedef _Float16 h8 __attribute__((ext_vector_type(8)));
typedef float f32x4 __attribute__((ext_vector_type(4)));

__device__ inline h8 shflx8(h8 v, int m) {
    int4 i = __builtin_bit_cast(int4, v);
    i.x = __shfl_xor(i.x, m);
    i.y = __shfl_xor(i.y, m);
    i.z = __shfl_xor(i.z, m);
    i.w = __shfl_xor(i.w, m);
    return __builtin_bit_cast(h8, i);
}

__device__ inline float fast_tanh(float v) {
    float e = __expf(2.0f * v);
    return 1.0f - 2.0f / (e + 1.0f);
}

#define BSHIFT 9
#define BSIZE  512
#define NBMAX  512
#define NREP   8
#define RCAP   1024
#define CAP    (NREP * RCAP)
#define MAXPER 4992

__device__ inline float b1map(const float* W1p, const float* W1n, int k, int c)
{
    if (c < 32) {
        if (k < 64)   return W1p[k * 32 + c];
        if (k >= 128) return W1p[(k - 64) * 32 + c];
        return 0.0f;
    } else {
        int cn = c - 32;
        if (k >= 64)  return W1n[(k - 64) * 32 + cn];
        return 0.0f;
    }
}

__device__ inline float b2map(const float* W2p, const float* W2n, int k, int c)
{
    if (c < 32) {
        if (k < 32)               return W2p[k * 32 + c];
        if (k >= 96 && k < 128)   return W2p[(k - 96 + 32) * 32 + c];
        if (k >= 128 && k < 160)  return W2p[(k - 128 + 64) * 32 + c];
        return 0.0f;
    } else {
        int cn = c - 32;
        if (k >= 32 && k < 64)    return W2n[(k - 32) * 32 + cn];
        if (k >= 64 && k < 96)    return W2n[(k - 64 + 32) * 32 + cn];
        if (k >= 160)             return W2n[(k - 160 + 64) * 32 + cn];
        return 0.0f;
    }
}

__device__ inline int nmap(int g, int r) {
    return 32 * (16 * (g >> 3) + (r >> 2)) + 4 * (g & 7) + (r & 3);
}

// ---- merged: bucket (blocks [0,bblocks)) | cvt (grid-stride) | prep -------
// (R16 verbatim)

__global__ void __launch_bounds__(256) mega_k(
    const int* __restrict__ pos, const int* __restrict__ neg,
    int* __restrict__ pcntR, unsigned* __restrict__ ebuf,
    int E, int n, int nb, int bblocks,
    const float4* __restrict__ x, h4* __restrict__ xh, int n4, int cvtBlocks,
    const float* __restrict__ W1p, const float* __restrict__ W1n,
    const float* __restrict__ W2p, const float* __restrict__ W2n,
    _Float16* __restrict__ Bpack)
{
    int tid = threadIdx.x;
    int bid = blockIdx.x;

    if (bid >= bblocks) {
        int cb = bid - bblocks;
        if (cb < cvtBlocks) {
            int gs = cvtBlocks * 256;
            for (int i = cb * 256 + tid; i < n4; i += gs) {
                float4 v = x[i];
                h4 o = { (_Float16)v.x, (_Float16)v.y, (_Float16)v.z, (_Float16)v.w };
                xh[i] = o;
            }
        } else {
            int slot = (cb - cvtBlocks) * 256 + tid;
            if (slot < 2 * 24 * 64) {
                int mat  = slot / (24 * 64);
                int rem  = slot % (24 * 64);
                int fg   = rem / 64;
                int lane = rem % 64;
                int kk = fg >> 2, nt = fg & 3;
                int g = lane >> 4, m = lane & 15;
                _Float16* dst = Bpack + (size_t)slot * 8;
                int c = nt * 16 + m;
                #pragma unroll
                for (int j = 0; j < 8; ++j) {
                    int k = kk * 32 + g * 8 + j;
                    float v = mat ? b2map(W2p, W2n, k, c) : b1map(W1p, W1n, k, c);
                    dst[j] = (_Float16)v;
                }
            }
        }
        return;
    }

    __shared__ int cnt[NBMAX], gbase[NBMAX], lofs[NBMAX], sc2[256];
    __shared__ unsigned erec[MAXPER], sorted[MAXPER];
    __shared__ unsigned short ep[MAXPER], pd[MAXPER];
    int rep = bid & (NREP - 1);
    int per = (2 * E + bblocks - 1) / bblocks;
    int e0 = bid * per;
    int e1 = min(e0 + per, 2 * E);
    int cntloc = e1 - e0;

    for (int i = tid; i < nb; i += 256) cnt[i] = 0;
    __syncthreads();
    for (int e = e0 + tid; e < e1; e += 256) {
        int nd, sr;
        if (e < E) { nd = pos[E + e];                 sr = pos[e]; }
        else       { int ee = e - E; nd = n + neg[E + ee]; sr = neg[ee]; }
        int p = nd >> BSHIFT;
        int li = e - e0;
        erec[li] = ((unsigned)(nd & (BSIZE - 1)) << 17) | (unsigned)sr;
        ep[li] = (unsigned short)p;
        atomicAdd(&cnt[p], 1);
    }
    __syncthreads();
    for (int i = tid; i < nb; i += 256) {
        int c = cnt[i];
        gbase[i] = c ? atomicAdd(&pcntR[rep * NBMAX + i], c) : 0;
    }
    {
        int a0 = (2 * tid     < nb) ? cnt[2 * tid]     : 0;
        int a1 = (2 * tid + 1 < nb) ? cnt[2 * tid + 1] : 0;
        int s = a0 + a1;
        sc2[tid] = s;
        __syncthreads();
        for (int off = 1; off < 256; off <<= 1) {
            int t = (tid >= off) ? sc2[tid - off] : 0;
            __syncthreads();
            sc2[tid] += t;
            __syncthreads();
        }
        int excl = sc2[tid] - s;
        if (2 * tid     < nb) lofs[2 * tid]     = excl;
        if (2 * tid + 1 < nb) lofs[2 * tid + 1] = excl + a0;
    }
    __syncthreads();
    for (int i = tid; i < nb; i += 256) cnt[i] = 0;
    __syncthreads();
    for (int li = tid; li < cntloc; li += 256) {
        int p = ep[li];
        int r = atomicAdd(&cnt[p], 1);
        int idx = lofs[p] + r;
        sorted[idx] = erec[li];
        pd[idx] = (unsigned short)p;
    }
    __syncthreads();
    for (int t = tid; t < cntloc; t += 256) {
        int p = pd[t];
        int g = gbase[p] + (t - lofs[p]);
        if (g < RCAP)
            ebuf[(size_t)p * CAP + rep * RCAP + g] = sorted[t];
    }
}

// scatter_k (R16 verbatim, 1024 threads)
__global__ void __launch_bounds__(1024) scatter_k(
    const unsigned* __restrict__ ebuf, const int* __restrict__ pcntR,
    int* __restrict__ cur, int* __restrict__ col, int n, int nb)
{
    __shared__ int lcnt[BSIZE], lbase[BSIZE], sc[256], bb[NBMAX], crp[NREP];
    __shared__ int lcol[CAP];
    int p = blockIdx.x;
    int tid = threadIdx.x;
    int n2 = 2 * n;
    int lo = p << BSHIFT;
    int nn = min(BSIZE, n2 - lo);
    const unsigned* bbuf = ebuf + (size_t)p * CAP;

    if (tid < NREP) crp[tid] = min(pcntR[tid * NBMAX + p], RCAP);
    {
        int a0 = 0, a1 = 0, s = 0;
        if (tid < 256) {
            #pragma unroll
            for (int r = 0; r < NREP; ++r) {
                if (2 * tid     < nb) a0 += min(pcntR[r * NBMAX + 2 * tid],     RCAP);
                if (2 * tid + 1 < nb) a1 += min(pcntR[r * NBMAX + 2 * tid + 1], RCAP);
            }
            s = a0 + a1;
            sc[tid] = s;
        }
        __syncthreads();
        for (int off = 1; off < 256; off <<= 1) {
            int t = (tid < 256 && tid >= off) ? sc[tid - off] : 0;
            __syncthreads();
            if (tid < 256) sc[tid] += t;
            __syncthreads();
        }
        if (tid < 256) {
            int excl = sc[tid] - s;
            bb[2 * tid]     = excl;
            bb[2 * tid + 1] = excl + a0;
        }
    }
    for (int i = tid; i < BSIZE; i += 1024) lcnt[i] = 0;
    __syncthreads();
    int cnttot = crp[0] + crp[1] + crp[2] + crp[3] +
                 crp[4] + crp[5] + crp[6] + crp[7];
    #pragma unroll
    for (int r = 0; r < NREP; ++r) {
        int c = crp[r];
        const unsigned* buf = bbuf + r * RCAP;
        for (int i = tid; i < c; i += 1024)
            atomicAdd(&lcnt[buf[i] >> 17], 1);
    }
    __syncthreads();
    {
        int a0 = 0, a1 = 0, s = 0;
        if (tid < 256) {
            a0 = lcnt[2 * tid]; a1 = lcnt[2 * tid + 1];
            s = a0 + a1;
            sc[tid] = s;
        }
        __syncthreads();
        for (int off = 1; off < 256; off <<= 1) {
            int t = (tid < 256 && tid >= off) ? sc[tid - off] : 0;
            __syncthreads();
            if (tid < 256) sc[tid] += t;
            __syncthreads();
        }
        if (tid < 256) {
            int excl = sc[tid] - s;
            lbase[2 * tid]     = excl;
            lbase[2 * tid + 1] = excl + a0;
        }
    }
    __syncthreads();
    int gb = bb[p];
    for (int i = tid; i < nn; i += 1024)
        cur[lo + i] = gb + lbase[i] + lcnt[i];
    __syncthreads();
    #pragma unroll
    for (int r = 0; r < NREP; ++r) {
        int c = crp[r];
        const unsigned* buf = bbuf + r * RCAP;
        for (int i = tid; i < c; i += 1024) {
            unsigned v = buf[i];
            int slot = atomicAdd(&lbase[v >> 17], 1);
            lcol[slot] = (int)(v & 0x1FFFFu);
        }
    }
    __syncthreads();
    for (int t = tid; t < cnttot; t += 1024)
        col[gb + t] = lcol[t];
}

// ------------------- fused layer: agg -> scoped barrier -> gemm -------------
// agg phase identical to frozen agg_k, but ag written via AGENT-scope 8B
// atomic stores (L2-bypass -> no flush needed at the barrier). Barrier:
// one release-atomicAdd per block; tid0 relaxed spin + s_sleep; failsafe
// bound (wrong-answer, never hang). gemm phase reads ag via agent-scope
// loads; x/z operand from normal (L2-cached) loads; out via normal stores.

__global__ void __launch_bounds__(256, 7) layer_k(
    const h8* __restrict__ feat8,
    const int* __restrict__ cur, const int* __restrict__ col,
    const h8* __restrict__ Bp,
    const float* __restrict__ bp, const float* __restrict__ bn,
    unsigned long long* __restrict__ ag64,
    float* __restrict__ outf, _Float16* __restrict__ outh,
    int f32out, int n, int ntiles, int* __restrict__ bar, int nblk)
{
    __shared__ _Float16 A_lds[64 * 132];   // 16.9 KB (ag tile only)
    int tid = threadIdx.x;
    int wave = tid >> 6, lane = tid & 63;

    // ---- phase 1: aggregation ----
    {
        int s = lane >> 2, f = lane & 3;
        int list = s >> 3;
        int sub = s & 7;
        int stride = gridDim.x * 4;
        for (int node = blockIdx.x * 4 + wave; node < n; node += stride) {
            int idx = list ? n + node : node;
            int r0 = idx ? cur[idx - 1] : 0;
            int r1 = cur[idx];
            h8 acc0 = {}, acc1 = {};
            #pragma unroll 2
            for (int it = r0 + sub; it < r1; it += 8) {
                unsigned srcb = (unsigned)col[it] * 8;
                acc0 = acc0 + feat8[srcb + f];
                acc1 = acc1 + feat8[srcb + 4 + f];
            }
            acc0 = acc0 + shflx8(acc0, 4);
            acc1 = acc1 + shflx8(acc1, 4);
            acc0 = acc0 + shflx8(acc0, 8);
            acc1 = acc1 + shflx8(acc1, 8);
            acc0 = acc0 + shflx8(acc0, 16);
            acc1 = acc1 + shflx8(acc1, 16);
            _Float16 inv = (_Float16)(1.0f / (float)max(r1 - r0, 1));
            h8 iv = { inv, inv, inv, inv, inv, inv, inv, inv };
            if (sub == 0) {
                h8 v0 = acc0 * iv, v1 = acc1 * iv;
                ulonglong2 u0 = __builtin_bit_cast(ulonglong2, v0);
                ulonglong2 u1 = __builtin_bit_cast(ulonglong2, v1);
                size_t b0 = (size_t)(unsigned)(node * 16 + list * 8 + f) * 2;
                size_t b1 = (size_t)(unsigned)(node * 16 + list * 8 + 4 + f) * 2;
                __hip_atomic_store(&ag64[b0],     u0.x, __ATOMIC_RELAXED, __HIP_MEMORY_SCOPE_AGENT);
                __hip_atomic_store(&ag64[b0 + 1], u0.y, __ATOMIC_RELAXED, __HIP_MEMORY_SCOPE_AGENT);
                __hip_atomic_store(&ag64[b1],     u1.x, __ATOMIC_RELAXED, __HIP_MEMORY_SCOPE_AGENT);
                __hip_atomic_store(&ag64[b1 + 1], u1.y, __ATOMIC_RELAXED, __HIP_MEMORY_SCOPE_AGENT);
            }
        }
    }

    // ---- scoped grid barrier (no cache flush) ----
    __syncthreads();
    if (tid == 0) {
        __hip_atomic_fetch_add(bar, 1, __ATOMIC_RELEASE, __HIP_MEMORY_SCOPE_AGENT);
        long spins = 0;
        while (__hip_atomic_load(bar, __ATOMIC_ACQUIRE, __HIP_MEMORY_SCOPE_AGENT) < nblk) {
            __builtin_amdgcn_s_sleep(16);
            if (++spins > (1L << 20)) break;   // failsafe: ~0.4s, never in practice
        }
    }
    __syncthreads();

    // ---- phase 2: gemm tiles ----
    int m = lane & 15, g4 = lane >> 4;
    for (int t = blockIdx.x; t < ntiles; t += gridDim.x) {
        __syncthreads();
        for (int ch = tid; ch < 64 * 16; ch += 256) {       // stage ag rows
            int r = ch >> 4, c = ch & 15;
            int row = min(nmap(t, r), n - 1);
            size_t bi = ((size_t)row * 16 + c) * 2;
            unsigned long long w0 = __hip_atomic_load(&ag64[bi],     __ATOMIC_RELAXED, __HIP_MEMORY_SCOPE_AGENT);
            unsigned long long w1 = __hip_atomic_load(&ag64[bi + 1], __ATOMIC_RELAXED, __HIP_MEMORY_SCOPE_AGENT);
            ulonglong2 u; u.x = w0; u.y = w1;
            *(h8*)&A_lds[r * 132 + c * 8] = __builtin_bit_cast(h8, u);
        }
        __syncthreads();

        int rowm = min(nmap(t, wave * 16 + m), n - 1);
        h8 a[6];
        #pragma unroll
        for (int kk = 0; kk < 4; ++kk)                      // ag part from LDS
            a[kk] = *(const h8*)&A_lds[(wave * 16 + m) * 132 + kk * 32 + g4 * 8];
        a[4] = feat8[(size_t)rowm * 8 + g4];                // x/z part, global
        a[5] = feat8[(size_t)rowm * 8 + 4 + g4];

        #pragma unroll
        for (int nt = 0; nt < 4; ++nt) {
            f32x4 acc = { 0.f, 0.f, 0.f, 0.f };
            #pragma unroll
            for (int kk = 0; kk < 6; ++kk) {
                h8 b = Bp[(kk * 4 + nt) * 64 + lane];
                acc = __builtin_amdgcn_mfma_f32_16x16x32_f16(a[kk], b, acc, 0, 0, 0);
            }
            int colc = nt * 16 + m;
            float bias = (colc < 32) ? bp[colc] : bn[colc - 32];
            #pragma unroll
            for (int reg = 0; reg < 4; ++reg) {
                int node = nmap(t, wave * 16 + g4 * 4 + reg);
                if (node < n) {
                    float val = fast_tanh(acc[reg] + bias);
                    if (f32out) outf[(size_t)node * 64 + colc] = val;
                    else        outh[(size_t)node * 64 + colc] = (_Float16)val;
                }
            }
        }
    }
}

// ============================== LAUNCHER ===================================

extern "C" void kernel_launch(void* const* d_in, const int* in_sizes, int n_in,
                              void* d_out, int out_size, void* d_ws, size_t ws_size,
                              hipStream_t stream)
{
    const float* x   = (const float*)d_in[0];
    const float* W1p = (const float*)d_in[1];
    const float* b1p = (const float*)d_in[2];
    const float* W1n = (const float*)d_in[3];
    const float* b1n = (const float*)d_in[4];
    const float* W2p = (const float*)d_in[5];
    const float* b2p = (const float*)d_in[6];
    const float* W2n = (const float*)d_in[7];
    const float* b2n = (const float*)d_in[8];
    const int*   pos = (const int*)d_in[9];
    const int*   neg = (const int*)d_in[10];

    int n = in_sizes[0] / 64;       // 100000
    int E = in_sizes[9] / 2;        // 1250000
    int n2 = 2 * n;
    int nb = (n2 + BSIZE - 1) / BSIZE;   // 391 buckets

    // ws: pcntR[8*512] | bar[8] | cur[2n] | col[2E] | Bpack | xh | ebuf/zh
    int*      pcntR = (int*)d_ws;
    int*      bar   = pcntR + NREP * NBMAX;
    int*      cur   = bar + 8;
    int*      col   = cur + n2;
    _Float16* Bpack = (_Float16*)(col + 2 * (size_t)E);
    _Float16* xh    = Bpack + 2 * 24 * 64 * 8;
    unsigned* ebuf  = (unsigned*)(xh + (size_t)n * 64);
    _Float16* zh    = (_Float16*)ebuf;            // aliases ebuf (dead after scatter)
    unsigned long long* ag64 = (unsigned long long*)d_out;

    hipMemsetAsync(pcntR, 0, (NREP * NBMAX + 8) * sizeof(int), stream);

    int bblocks = 512;
    int n4 = n * 16;
    int cvtBlocks = 512;

    mega_k<<<bblocks + cvtBlocks + 12, 256, 0, stream>>>(
        pos, neg, pcntR, ebuf, E, n, nb, bblocks,
        (const float4*)x, (h4*)xh, n4, cvtBlocks,
        W1p, W1n, W2p, W2n, Bpack);

    scatter_k<<<nb, 1024, 0, stream>>>(ebuf, pcntR, cur, col, n, nb);

    int lblocks = 1536;                            // capacity >= 1792 (LB 256,7)
    int ntiles = ((n + 511) / 512) * 8;            // 1568 (nmap bijective range)

    // layer 1: agg(x) -> ag (scoped) -> barrier -> gemm -> zh (fp16)
    layer_k<<<lblocks, 256, 0, stream>>>((const h8*)xh, cur, col,
                                         (const h8*)Bpack, b1p, b1n,
                                         ag64, nullptr, zh, 0, n, ntiles,
                                         bar + 0, lblocks);
    // layer 2: agg(z) -> ag (scoped) -> barrier -> gemm -> out (fp32)
    layer_k<<<lblocks, 256, 0, stream>>>((const h8*)zh, cur, col,
                                         (const h8*)(Bpack + 24 * 64 * 8),
                                         b2p, b2n, ag64,
                                         (float*)d_out, nullptr, 1, n, ntiles,
                                         bar + 4, lblocks);
}